// Round 1
// baseline (197.959 us; speedup 1.0000x reference)
//
#include <hip/hip_runtime.h>

#define TT_S 6
#define TT_H 8
#define TT_FF 16

__global__ __launch_bounds__(256) void tt_fused(
    const int* __restrict__ ids,
    const float* __restrict__ tok_emb, const float* __restrict__ pos_emb,
    const float* __restrict__ Wq, const float* __restrict__ bq,
    const float* __restrict__ Wk, const float* __restrict__ bk,
    const float* __restrict__ Wv, const float* __restrict__ bv,
    const float* __restrict__ Wo, const float* __restrict__ bo,
    const float* __restrict__ W1, const float* __restrict__ b1,
    const float* __restrict__ W2, const float* __restrict__ b2,
    const float* __restrict__ g1, const float* __restrict__ be1,
    const float* __restrict__ g2, const float* __restrict__ be2,
    float* __restrict__ out, int B)
{
  __shared__ __align__(16) float sm[1448];
  float* s_tok = sm;          // 800
  float* s_pos = sm + 800;    // 48
  float* s_wq  = sm + 848;    // 64
  float* s_bq  = sm + 912;    // 8
  float* s_wk  = sm + 920;    // 64
  float* s_bk  = sm + 984;    // 8
  float* s_wv  = sm + 992;    // 64
  float* s_bv  = sm + 1056;   // 8
  float* s_wo  = sm + 1064;   // 64
  float* s_bo  = sm + 1128;   // 8
  float* s_w1  = sm + 1136;   // 128
  float* s_b1  = sm + 1264;   // 16
  float* s_w2  = sm + 1280;   // 128
  float* s_b2  = sm + 1408;   // 8
  float* s_g1  = sm + 1416;   // 8
  float* s_be1 = sm + 1424;   // 8
  float* s_g2  = sm + 1432;   // 8
  float* s_be2 = sm + 1440;   // 8

  const int tid = threadIdx.x;
  for (int i = tid; i < 800; i += 256) s_tok[i] = tok_emb[i];
  if (tid < 48) s_pos[tid] = pos_emb[tid];
  if (tid < 64) { s_wq[tid] = Wq[tid]; s_wk[tid] = Wk[tid];
                  s_wv[tid] = Wv[tid]; s_wo[tid] = Wo[tid]; }
  if (tid < 128) { s_w1[tid] = W1[tid]; s_w2[tid] = W2[tid]; }
  if (tid < 16) s_b1[tid] = b1[tid];
  if (tid < 8) { s_bq[tid] = bq[tid]; s_bk[tid] = bk[tid]; s_bv[tid] = bv[tid];
                 s_bo[tid] = bo[tid]; s_b2[tid] = b2[tid];
                 s_g1[tid] = g1[tid]; s_be1[tid] = be1[tid];
                 s_g2[tid] = g2[tid]; s_be2[tid] = be2[tid]; }
  __syncthreads();

  const int b = blockIdx.x * 256 + tid;
  if (b >= B) return;

  // ---- load ids (3x int2, 8B-aligned since b*6*4 is a multiple of 8) ----
  const int* idp = ids + (size_t)b * TT_S;
  int2 i0 = *(const int2*)(idp + 0);
  int2 i1 = *(const int2*)(idp + 2);
  int2 i2 = *(const int2*)(idp + 4);
  int idv[TT_S] = { i0.x, i0.y, i1.x, i1.y, i2.x, i2.y };

  // ---- x = tok_emb[ids] + pos_emb ----
  float x[TT_S][TT_H];
  #pragma unroll
  for (int t = 0; t < TT_S; ++t) {
    const float4* tr = (const float4*)(s_tok + idv[t] * TT_H);
    float4 a0 = tr[0];
    float4 a1 = tr[1];
    x[t][0] = a0.x + s_pos[t*8+0];
    x[t][1] = a0.y + s_pos[t*8+1];
    x[t][2] = a0.z + s_pos[t*8+2];
    x[t][3] = a0.w + s_pos[t*8+3];
    x[t][4] = a1.x + s_pos[t*8+4];
    x[t][5] = a1.y + s_pos[t*8+5];
    x[t][6] = a1.z + s_pos[t*8+6];
    x[t][7] = a1.w + s_pos[t*8+7];
  }

  // ---- q,k,v projections; weight-outer order: each LDS weight feeds 6 FMAs ----
  float qm[TT_S][TT_H], km[TT_S][TT_H], vm[TT_S][TT_H];
  #pragma unroll
  for (int i = 0; i < TT_H; ++i) {
    float ak[TT_S], av[TT_S], aq[TT_S];
    float bki = s_bk[i], bvi = s_bv[i], bqi = s_bq[i];
    #pragma unroll
    for (int t = 0; t < TT_S; ++t) { ak[t] = bki; av[t] = bvi; aq[t] = bqi; }
    #pragma unroll
    for (int j = 0; j < TT_H; ++j) {
      float wk = s_wk[i*8+j], wv = s_wv[i*8+j], wq = s_wq[i*8+j];
      #pragma unroll
      for (int t = 0; t < TT_S; ++t) {
        ak[t] += x[t][j] * wk;
        av[t] += x[t][j] * wv;
        aq[t] += x[t][j] * wq;
      }
    }
    #pragma unroll
    for (int t = 0; t < TT_S; ++t) { km[t][i] = ak[t]; vm[t][i] = av[t]; qm[t][i] = aq[t]; }
  }

  // ---- attention per (s, head); attn overwrites qm in place ----
  #pragma unroll
  for (int s = 0; s < TT_S; ++s) {
    #pragma unroll
    for (int hh = 0; hh < 2; ++hh) {
      const int hb = hh * 4;
      float sc[TT_S];
      #pragma unroll
      for (int t = 0; t < TT_S; ++t) {
        float d = qm[s][hb+0] * km[t][hb+0];
        d += qm[s][hb+1] * km[t][hb+1];
        d += qm[s][hb+2] * km[t][hb+2];
        d += qm[s][hb+3] * km[t][hb+3];
        sc[t] = d * 0.5f;  // 1/sqrt(HD)=0.5
      }
      float m = fmaxf(fmaxf(fmaxf(sc[0], sc[1]), fmaxf(sc[2], sc[3])), fmaxf(sc[4], sc[5]));
      float sum = 0.f;
      #pragma unroll
      for (int t = 0; t < TT_S; ++t) { sc[t] = __expf(sc[t] - m); sum += sc[t]; }
      float inv = 1.f / sum;
      float a0 = 0.f, a1 = 0.f, a2 = 0.f, a3 = 0.f;
      #pragma unroll
      for (int t = 0; t < TT_S; ++t) {
        a0 += sc[t] * vm[t][hb+0];
        a1 += sc[t] * vm[t][hb+1];
        a2 += sc[t] * vm[t][hb+2];
        a3 += sc[t] * vm[t][hb+3];
      }
      qm[s][hb+0] = a0 * inv;
      qm[s][hb+1] = a1 * inv;
      qm[s][hb+2] = a2 * inv;
      qm[s][hb+3] = a3 * inv;
    }
  }

  // ---- o = attn @ Wo.T + bo ----
  float o[TT_S][TT_H];
  #pragma unroll
  for (int i = 0; i < TT_H; ++i) {
    float acc[TT_S];
    float boi = s_bo[i];
    #pragma unroll
    for (int t = 0; t < TT_S; ++t) acc[t] = boi;
    #pragma unroll
    for (int j = 0; j < TT_H; ++j) {
      float w = s_wo[i*8+j];
      #pragma unroll
      for (int t = 0; t < TT_S; ++t) acc[t] += qm[t][j] * w;
    }
    #pragma unroll
    for (int t = 0; t < TT_S; ++t) o[t][i] = acc[t];
  }

  // ---- h = LN(x + o) (g1, be1); h stored back into o ----
  #pragma unroll
  for (int t = 0; t < TT_S; ++t) {
    float r[TT_H];
    float mu = 0.f;
    #pragma unroll
    for (int i = 0; i < TT_H; ++i) { r[i] = x[t][i] + o[t][i]; mu += r[i]; }
    mu *= 0.125f;
    float var = 0.f;
    #pragma unroll
    for (int i = 0; i < TT_H; ++i) { float d = r[i] - mu; var += d * d; }
    var *= 0.125f;
    float rin = rsqrtf(var + 1e-5f);
    #pragma unroll
    for (int i = 0; i < TT_H; ++i)
      o[t][i] = (r[i] - mu) * rin * s_g1[i] + s_be1[i];
  }

  // ---- ffn1 = gelu_exact(h @ W1.T + b1) ----
  float f1[TT_S][TT_FF];
  #pragma unroll
  for (int f = 0; f < TT_FF; ++f) {
    float acc[TT_S];
    float b1f = s_b1[f];
    #pragma unroll
    for (int t = 0; t < TT_S; ++t) acc[t] = b1f;
    #pragma unroll
    for (int j = 0; j < TT_H; ++j) {
      float w = s_w1[f*8+j];
      #pragma unroll
      for (int t = 0; t < TT_S; ++t) acc[t] += o[t][j] * w;
    }
    #pragma unroll
    for (int t = 0; t < TT_S; ++t) {
      float u = acc[t];
      f1[t][f] = 0.5f * u * (1.f + erff(u * 0.70710678118654752f));
    }
  }

  // ---- y = ffn1 @ W2.T + b2 ----
  float y[TT_S][TT_H];
  #pragma unroll
  for (int i = 0; i < TT_H; ++i) {
    float acc[TT_S];
    float b2i = s_b2[i];
    #pragma unroll
    for (int t = 0; t < TT_S; ++t) acc[t] = b2i;
    #pragma unroll
    for (int f = 0; f < TT_FF; ++f) {
      float w = s_w2[i*16+f];
      #pragma unroll
      for (int t = 0; t < TT_S; ++t) acc[t] += f1[t][f] * w;
    }
    #pragma unroll
    for (int t = 0; t < TT_S; ++t) y[t][i] = acc[t];
  }

  // ---- out = LN(h + y) (g2, be2), float4 stores ----
  float* op = out + (size_t)b * (TT_S * TT_H);
  #pragma unroll
  for (int t = 0; t < TT_S; ++t) {
    float r[TT_H];
    float mu = 0.f;
    #pragma unroll
    for (int i = 0; i < TT_H; ++i) { r[i] = o[t][i] + y[t][i]; mu += r[i]; }
    mu *= 0.125f;
    float var = 0.f;
    #pragma unroll
    for (int i = 0; i < TT_H; ++i) { float d = r[i] - mu; var += d * d; }
    var *= 0.125f;
    float rin = rsqrtf(var + 1e-5f);
    float res[TT_H];
    #pragma unroll
    for (int i = 0; i < TT_H; ++i)
      res[i] = (r[i] - mu) * rin * s_g2[i] + s_be2[i];
    float4 v0; v0.x = res[0]; v0.y = res[1]; v0.z = res[2]; v0.w = res[3];
    float4 v1; v1.x = res[4]; v1.y = res[5]; v1.z = res[6]; v1.w = res[7];
    ((float4*)(op + t*8))[0] = v0;
    ((float4*)(op + t*8))[1] = v1;
  }
}

extern "C" void kernel_launch(void* const* d_in, const int* in_sizes, int n_in,
                              void* d_out, int out_size, void* d_ws, size_t ws_size,
                              hipStream_t stream) {
  const int*   ids = (const int*)  d_in[0];
  const float* tok = (const float*)d_in[1];
  const float* pos = (const float*)d_in[2];
  const float* Wq  = (const float*)d_in[3];
  const float* bq  = (const float*)d_in[4];
  const float* Wk  = (const float*)d_in[5];
  const float* bk  = (const float*)d_in[6];
  const float* Wv  = (const float*)d_in[7];
  const float* bv  = (const float*)d_in[8];
  const float* Wo  = (const float*)d_in[9];
  const float* bo  = (const float*)d_in[10];
  const float* W1  = (const float*)d_in[11];
  const float* b1  = (const float*)d_in[12];
  const float* W2  = (const float*)d_in[13];
  const float* b2  = (const float*)d_in[14];
  const float* g1  = (const float*)d_in[15];
  const float* be1 = (const float*)d_in[16];
  const float* g2  = (const float*)d_in[17];
  const float* be2 = (const float*)d_in[18];
  float* out = (float*)d_out;

  const int B = in_sizes[0] / TT_S;
  const int grid = (B + 255) / 256;
  hipLaunchKernelGGL(tt_fused, dim3(grid), dim3(256), 0, stream,
                     ids, tok, pos, Wq, bq, Wk, bk, Wv, bv, Wo, bo,
                     W1, b1, W2, b2, g1, be1, g2, be2, out, B);
}

// Round 2
// 166.215 us; speedup vs baseline: 1.1910x; 1.1910x over previous
//
#include <hip/hip_runtime.h>

#define TT_S 6
#define TT_H 8
#define TT_FF 16

__global__ __launch_bounds__(256, 3) void tt_fused(
    const int* __restrict__ ids,
    const float* __restrict__ tok_emb, const float* __restrict__ pos_emb,
    const float* __restrict__ Wq, const float* __restrict__ bq,
    const float* __restrict__ Wk, const float* __restrict__ bk,
    const float* __restrict__ Wv, const float* __restrict__ bv,
    const float* __restrict__ Wo, const float* __restrict__ bo,
    const float* __restrict__ W1, const float* __restrict__ b1,
    const float* __restrict__ W2, const float* __restrict__ b2,
    const float* __restrict__ g1, const float* __restrict__ be1,
    const float* __restrict__ g2, const float* __restrict__ be2,
    float* __restrict__ out, int B)
{
  // LDS holds ONLY the token-embedding gather table. All weights/biases/LN
  // params are read with wave-uniform constant-indexed addresses -> the
  // compiler scalarizes them to s_load (SGPR), off the LDS and VALU pipes.
  __shared__ __align__(16) float s_tok[800];
  const int tid = threadIdx.x;
  for (int i = tid; i < 800; i += 256) s_tok[i] = tok_emb[i];
  __syncthreads();

  const int b = blockIdx.x * 256 + tid;
  if (b >= B) return;

  // ---- load 6 ids; pack into 48 bits (VOCAB=100 < 256) for the rolled loop ----
  const int* idp = ids + (size_t)b * TT_S;
  int2 i0 = *(const int2*)(idp + 0);
  int2 i1 = *(const int2*)(idp + 2);
  int2 i2 = *(const int2*)(idp + 4);
  unsigned long long P =
      (unsigned long long)(unsigned)i0.x        |
      ((unsigned long long)(unsigned)i0.y << 8) |
      ((unsigned long long)(unsigned)i1.x << 16)|
      ((unsigned long long)(unsigned)i1.y << 24)|
      ((unsigned long long)(unsigned)i2.x << 32)|
      ((unsigned long long)(unsigned)i2.y << 40);

  // ---- build K,V (96 regs) with x rows transient; weight-outer for SGPR reuse ----
  float km[TT_S][TT_H], vm[TT_S][TT_H];
  {
    float x[TT_S][TT_H];
    const int idv[TT_S] = { i0.x, i0.y, i1.x, i1.y, i2.x, i2.y };
    #pragma unroll
    for (int t = 0; t < TT_S; ++t) {
      const float4* tr = (const float4*)(s_tok + idv[t] * TT_H);
      float4 a0 = tr[0];
      float4 a1 = tr[1];
      x[t][0] = a0.x + pos_emb[t*8+0];
      x[t][1] = a0.y + pos_emb[t*8+1];
      x[t][2] = a0.z + pos_emb[t*8+2];
      x[t][3] = a0.w + pos_emb[t*8+3];
      x[t][4] = a1.x + pos_emb[t*8+4];
      x[t][5] = a1.y + pos_emb[t*8+5];
      x[t][6] = a1.z + pos_emb[t*8+6];
      x[t][7] = a1.w + pos_emb[t*8+7];
    }
    #pragma unroll
    for (int i = 0; i < TT_H; ++i) {
      float ak[TT_S], av[TT_S];
      float bki = bk[i], bvi = bv[i];
      #pragma unroll
      for (int t = 0; t < TT_S; ++t) { ak[t] = bki; av[t] = bvi; }
      #pragma unroll
      for (int j = 0; j < TT_H; ++j) {
        float wk = Wk[i*8+j], wv = Wv[i*8+j];
        #pragma unroll
        for (int t = 0; t < TT_S; ++t) {
          ak[t] = fmaf(x[t][j], wk, ak[t]);
          av[t] = fmaf(x[t][j], wv, av[t]);
        }
      }
      #pragma unroll
      for (int t = 0; t < TT_S; ++t) { km[t][i] = ak[t]; vm[t][i] = av[t]; }
    }
  } // x dies here

  // ---- stream one output row per iteration; rolled to cap VGPR pressure ----
  float* op = out + (size_t)b * (TT_S * TT_H);
  #pragma unroll 1
  for (int s = 0; s < TT_S; ++s) {
    const int tok = (int)((P >> (s * 8)) & 0xFF);
    const float4* xr = (const float4*)(s_tok + tok * TT_H);
    float4 a0 = xr[0];
    float4 a1 = xr[1];
    float xs[TT_H];
    xs[0] = a0.x + pos_emb[s*8+0];
    xs[1] = a0.y + pos_emb[s*8+1];
    xs[2] = a0.z + pos_emb[s*8+2];
    xs[3] = a0.w + pos_emb[s*8+3];
    xs[4] = a1.x + pos_emb[s*8+4];
    xs[5] = a1.y + pos_emb[s*8+5];
    xs[6] = a1.z + pos_emb[s*8+6];
    xs[7] = a1.w + pos_emb[s*8+7];

    // q_s (scale 1/sqrt(HD)=0.5 folded in)
    float qs[TT_H];
    #pragma unroll
    for (int i = 0; i < TT_H; ++i) {
      float a = bq[i];
      #pragma unroll
      for (int j = 0; j < TT_H; ++j) a = fmaf(xs[j], Wq[i*8+j], a);
      qs[i] = a * 0.5f;
    }

    // attention (2 heads); softmax without max-sub (scores bounded ~1)
    float attn[TT_H];
    #pragma unroll
    for (int hh = 0; hh < 2; ++hh) {
      const int hb = hh * 4;
      float sc[TT_S];
      float sum = 0.f;
      #pragma unroll
      for (int t = 0; t < TT_S; ++t) {
        float d = qs[hb+0] * km[t][hb+0];
        d = fmaf(qs[hb+1], km[t][hb+1], d);
        d = fmaf(qs[hb+2], km[t][hb+2], d);
        d = fmaf(qs[hb+3], km[t][hb+3], d);
        sc[t] = __expf(d);
        sum += sc[t];
      }
      float inv = __builtin_amdgcn_rcpf(sum);
      float a0_ = 0.f, a1_ = 0.f, a2_ = 0.f, a3_ = 0.f;
      #pragma unroll
      for (int t = 0; t < TT_S; ++t) {
        a0_ = fmaf(sc[t], vm[t][hb+0], a0_);
        a1_ = fmaf(sc[t], vm[t][hb+1], a1_);
        a2_ = fmaf(sc[t], vm[t][hb+2], a2_);
        a3_ = fmaf(sc[t], vm[t][hb+3], a3_);
      }
      attn[hb+0] = a0_ * inv;
      attn[hb+1] = a1_ * inv;
      attn[hb+2] = a2_ * inv;
      attn[hb+3] = a3_ * inv;
    }

    // o = attn @ Wo.T + bo; residual; LN1
    float r[TT_H];
    float mu = 0.f;
    #pragma unroll
    for (int i = 0; i < TT_H; ++i) {
      float o = bo[i];
      #pragma unroll
      for (int j = 0; j < TT_H; ++j) o = fmaf(attn[j], Wo[i*8+j], o);
      r[i] = xs[i] + o;
      mu += r[i];
    }
    mu *= 0.125f;
    float var = 0.f;
    #pragma unroll
    for (int i = 0; i < TT_H; ++i) { float d = r[i] - mu; var = fmaf(d, d, var); }
    var *= 0.125f;
    float rin = __builtin_amdgcn_rsqf(var + 1e-5f);
    float hr[TT_H];
    #pragma unroll
    for (int i = 0; i < TT_H; ++i)
      hr[i] = fmaf((r[i] - mu) * rin, g1[i], be1[i]);

    // ffn1 with tanh-form gelu: gelu(u) = u*e/(e+1), e = exp(2*sqrt(2/pi)*u*(1+0.044715u^2))
    float f1[TT_FF];
    #pragma unroll
    for (int f = 0; f < TT_FF; ++f) {
      float u = b1[f];
      #pragma unroll
      for (int j = 0; j < TT_H; ++j) u = fmaf(hr[j], W1[f*8+j], u);
      float u2 = u * u;
      float p  = fmaf(0.044715f, u2, 1.0f);
      float z2 = fminf(1.5957691216057308f * u * p, 60.f);
      float e  = __expf(z2);
      f1[f] = u * e * __builtin_amdgcn_rcpf(e + 1.0f);
    }

    // y = f1 @ W2.T + b2; residual; LN2; store
    float r2[TT_H];
    float mu2 = 0.f;
    #pragma unroll
    for (int i = 0; i < TT_H; ++i) {
      float y = b2[i];
      #pragma unroll
      for (int f = 0; f < TT_FF; ++f) y = fmaf(f1[f], W2[i*16+f], y);
      r2[i] = hr[i] + y;
      mu2 += r2[i];
    }
    mu2 *= 0.125f;
    float var2 = 0.f;
    #pragma unroll
    for (int i = 0; i < TT_H; ++i) { float d = r2[i] - mu2; var2 = fmaf(d, d, var2); }
    var2 *= 0.125f;
    float rin2 = __builtin_amdgcn_rsqf(var2 + 1e-5f);
    float res[TT_H];
    #pragma unroll
    for (int i = 0; i < TT_H; ++i)
      res[i] = fmaf((r2[i] - mu2) * rin2, g2[i], be2[i]);

    float4 v0; v0.x = res[0]; v0.y = res[1]; v0.z = res[2]; v0.w = res[3];
    float4 v1; v1.x = res[4]; v1.y = res[5]; v1.z = res[6]; v1.w = res[7];
    ((float4*)(op + s*8))[0] = v0;
    ((float4*)(op + s*8))[1] = v1;
  }
}

extern "C" void kernel_launch(void* const* d_in, const int* in_sizes, int n_in,
                              void* d_out, int out_size, void* d_ws, size_t ws_size,
                              hipStream_t stream) {
  const int*   ids = (const int*)  d_in[0];
  const float* tok = (const float*)d_in[1];
  const float* pos = (const float*)d_in[2];
  const float* Wq  = (const float*)d_in[3];
  const float* bq  = (const float*)d_in[4];
  const float* Wk  = (const float*)d_in[5];
  const float* bk  = (const float*)d_in[6];
  const float* Wv  = (const float*)d_in[7];
  const float* bv  = (const float*)d_in[8];
  const float* Wo  = (const float*)d_in[9];
  const float* bo  = (const float*)d_in[10];
  const float* W1  = (const float*)d_in[11];
  const float* b1  = (const float*)d_in[12];
  const float* W2  = (const float*)d_in[13];
  const float* b2  = (const float*)d_in[14];
  const float* g1  = (const float*)d_in[15];
  const float* be1 = (const float*)d_in[16];
  const float* g2  = (const float*)d_in[17];
  const float* be2 = (const float*)d_in[18];
  float* out = (float*)d_out;

  const int B = in_sizes[0] / TT_S;
  const int grid = (B + 255) / 256;
  hipLaunchKernelGGL(tt_fused, dim3(grid), dim3(256), 0, stream,
                     ids, tok, pos, Wq, bq, Wk, bk, Wv, bv, Wo, bo,
                     W1, b1, W2, b2, g1, be1, g2, be2, out, B);
}

// Round 3
// 142.800 us; speedup vs baseline: 1.3863x; 1.1640x over previous
//
#include <hip/hip_runtime.h>

#define TT_S 6
#define TT_H 8
#define TT_FF 16
#define SEQ_PER_BLK 64
#define BLK (SEQ_PER_BLK * TT_S)   /* 384 threads = 6 waves */
#define KV_STRIDE 108              /* 96 floats + 12 pad; 108 mod 32 = 12 -> seqs spread over 8 bank groups */

__global__ __launch_bounds__(BLK, 6) void tt_fused(
    const int* __restrict__ ids,
    const float* __restrict__ tok_emb, const float* __restrict__ pos_emb,
    const float* __restrict__ Wq, const float* __restrict__ bq,
    const float* __restrict__ Wk, const float* __restrict__ bk,
    const float* __restrict__ Wv, const float* __restrict__ bv,
    const float* __restrict__ Wo, const float* __restrict__ bo,
    const float* __restrict__ W1, const float* __restrict__ b1,
    const float* __restrict__ W2, const float* __restrict__ b2,
    const float* __restrict__ g1, const float* __restrict__ be1,
    const float* __restrict__ g2, const float* __restrict__ be2,
    float* __restrict__ out, int B)
{
  __shared__ __align__(16) float s_tok[800];
  __shared__ __align__(16) float s_pos[48];
  __shared__ __align__(16) float s_kv[SEQ_PER_BLK * KV_STRIDE];

  const int tid = threadIdx.x;
  for (int i = tid; i < 800; i += BLK) s_tok[i] = tok_emb[i];
  if (tid < 48) s_pos[tid] = pos_emb[tid];
  __syncthreads();

  const int s_loc = tid / TT_S;        // local sequence 0..63
  const int t     = tid - s_loc * TT_S; // token row 0..5
  const int seq_g = blockIdx.x * SEQ_PER_BLK + s_loc;
  const bool valid = (seq_g < B);

  // ---- token id: fully coalesced (ids laid out [seq][t], tid == seq_loc*6+t) ----
  const size_t gidx = (size_t)blockIdx.x * BLK + tid;
  const int id = valid ? ids[gidx] : 0;

  // ---- x row = tok_emb[id] + pos_emb[t] (LDS gathers, b128) ----
  const float4* tr = (const float4*)(s_tok + id * TT_H);
  float4 a0 = tr[0];
  float4 a1 = tr[1];
  const float4* pr = (const float4*)(s_pos + t * TT_H);
  float4 p0 = pr[0];
  float4 p1 = pr[1];
  float xs[TT_H];
  xs[0] = a0.x + p0.x; xs[1] = a0.y + p0.y; xs[2] = a0.z + p0.z; xs[3] = a0.w + p0.w;
  xs[4] = a1.x + p1.x; xs[5] = a1.y + p1.y; xs[6] = a1.z + p1.z; xs[7] = a1.w + p1.w;

  // ---- k,v for OWN token only; share via LDS ----
  {
    float kr[TT_H], vr[TT_H];
    #pragma unroll
    for (int i = 0; i < TT_H; ++i) {
      float ak = bk[i], av = bv[i];
      #pragma unroll
      for (int j = 0; j < TT_H; ++j) {
        ak = fmaf(xs[j], Wk[i*8+j], ak);
        av = fmaf(xs[j], Wv[i*8+j], av);
      }
      kr[i] = ak; vr[i] = av;
    }
    float* kvp = s_kv + s_loc * KV_STRIDE + t * 16;
    float4 w0; w0.x = kr[0]; w0.y = kr[1]; w0.z = kr[2]; w0.w = kr[3];
    float4 w1; w1.x = kr[4]; w1.y = kr[5]; w1.z = kr[6]; w1.w = kr[7];
    float4 w2; w2.x = vr[0]; w2.y = vr[1]; w2.z = vr[2]; w2.w = vr[3];
    float4 w3; w3.x = vr[4]; w3.y = vr[5]; w3.z = vr[6]; w3.w = vr[7];
    ((float4*)kvp)[0] = w0;
    ((float4*)kvp)[1] = w1;
    ((float4*)kvp)[2] = w2;
    ((float4*)kvp)[3] = w3;
  }
  __syncthreads();

  // ---- q row (1/sqrt(HD)=0.5 folded) ----
  float qs[TT_H];
  #pragma unroll
  for (int i = 0; i < TT_H; ++i) {
    float a = bq[i];
    #pragma unroll
    for (int j = 0; j < TT_H; ++j) a = fmaf(xs[j], Wq[i*8+j], a);
    qs[i] = a * 0.5f;
  }

  // ---- online attention over the 6 K/V rows (no max-sub; scores bounded small) ----
  float acc[TT_H] = {0.f,0.f,0.f,0.f,0.f,0.f,0.f,0.f};
  float sum0 = 0.f, sum1 = 0.f;
  const float4* kvb = (const float4*)(s_kv + s_loc * KV_STRIDE);
  #pragma unroll
  for (int t2 = 0; t2 < TT_S; ++t2) {
    float4 ka = kvb[t2*4+0];   // k dims 0..3  (head 0)
    float4 kb = kvb[t2*4+1];   // k dims 4..7  (head 1)
    float4 va = kvb[t2*4+2];   // v dims 0..3
    float4 vb = kvb[t2*4+3];   // v dims 4..7
    float d0 = qs[0]*ka.x;
    d0 = fmaf(qs[1], ka.y, d0);
    d0 = fmaf(qs[2], ka.z, d0);
    d0 = fmaf(qs[3], ka.w, d0);
    float d1 = qs[4]*kb.x;
    d1 = fmaf(qs[5], kb.y, d1);
    d1 = fmaf(qs[6], kb.z, d1);
    d1 = fmaf(qs[7], kb.w, d1);
    float e0 = __expf(d0);
    float e1 = __expf(d1);
    sum0 += e0; sum1 += e1;
    acc[0] = fmaf(e0, va.x, acc[0]);
    acc[1] = fmaf(e0, va.y, acc[1]);
    acc[2] = fmaf(e0, va.z, acc[2]);
    acc[3] = fmaf(e0, va.w, acc[3]);
    acc[4] = fmaf(e1, vb.x, acc[4]);
    acc[5] = fmaf(e1, vb.y, acc[5]);
    acc[6] = fmaf(e1, vb.z, acc[6]);
    acc[7] = fmaf(e1, vb.w, acc[7]);
  }
  {
    float inv0 = __builtin_amdgcn_rcpf(sum0);
    float inv1 = __builtin_amdgcn_rcpf(sum1);
    acc[0] *= inv0; acc[1] *= inv0; acc[2] *= inv0; acc[3] *= inv0;
    acc[4] *= inv1; acc[5] *= inv1; acc[6] *= inv1; acc[7] *= inv1;
  }

  // ---- o = attn @ Wo.T + bo; residual; LN1 ----
  float r[TT_H];
  float mu = 0.f;
  #pragma unroll
  for (int i = 0; i < TT_H; ++i) {
    float o = bo[i];
    #pragma unroll
    for (int j = 0; j < TT_H; ++j) o = fmaf(acc[j], Wo[i*8+j], o);
    r[i] = xs[i] + o;
    mu += r[i];
  }
  mu *= 0.125f;
  float var = 0.f;
  #pragma unroll
  for (int i = 0; i < TT_H; ++i) { float d = r[i] - mu; var = fmaf(d, d, var); }
  var *= 0.125f;
  float rin = __builtin_amdgcn_rsqf(var + 1e-5f);
  float hr[TT_H];
  #pragma unroll
  for (int i = 0; i < TT_H; ++i)
    hr[i] = fmaf((r[i] - mu) * rin, g1[i], be1[i]);

  // ---- ffn1: gelu(u) = u*e/(e+1), e = exp(2*0.7978845608*u*(1+0.044715u^2)) ----
  float f1[TT_FF];
  #pragma unroll
  for (int f = 0; f < TT_FF; ++f) {
    float u = b1[f];
    #pragma unroll
    for (int j = 0; j < TT_H; ++j) u = fmaf(hr[j], W1[f*8+j], u);
    float u2 = u * u;
    float p  = fmaf(0.044715f, u2, 1.0f);
    float z2 = fminf(1.5957691216057308f * u * p, 60.f);
    float e  = __expf(z2);
    f1[f] = u * e * __builtin_amdgcn_rcpf(e + 1.0f);
  }

  // ---- y = f1 @ W2.T + b2; residual; LN2; store ----
  float r2[TT_H];
  float mu2 = 0.f;
  #pragma unroll
  for (int i = 0; i < TT_H; ++i) {
    float y = b2[i];
    #pragma unroll
    for (int f = 0; f < TT_FF; ++f) y = fmaf(f1[f], W2[i*16+f], y);
    r2[i] = hr[i] + y;
    mu2 += r2[i];
  }
  mu2 *= 0.125f;
  float var2 = 0.f;
  #pragma unroll
  for (int i = 0; i < TT_H; ++i) { float d = r2[i] - mu2; var2 = fmaf(d, d, var2); }
  var2 *= 0.125f;
  float rin2 = __builtin_amdgcn_rsqf(var2 + 1e-5f);
  float res[TT_H];
  #pragma unroll
  for (int i = 0; i < TT_H; ++i)
    res[i] = fmaf((r2[i] - mu2) * rin2, g2[i], be2[i]);

  if (valid) {
    float* op = out + gidx * TT_H;  // == seq_g*48 + t*8 ; consecutive lanes -> consecutive 32B
    float4 v0; v0.x = res[0]; v0.y = res[1]; v0.z = res[2]; v0.w = res[3];
    float4 v1; v1.x = res[4]; v1.y = res[5]; v1.z = res[6]; v1.w = res[7];
    ((float4*)op)[0] = v0;
    ((float4*)op)[1] = v1;
  }
}

extern "C" void kernel_launch(void* const* d_in, const int* in_sizes, int n_in,
                              void* d_out, int out_size, void* d_ws, size_t ws_size,
                              hipStream_t stream) {
  const int*   ids = (const int*)  d_in[0];
  const float* tok = (const float*)d_in[1];
  const float* pos = (const float*)d_in[2];
  const float* Wq  = (const float*)d_in[3];
  const float* bq  = (const float*)d_in[4];
  const float* Wk  = (const float*)d_in[5];
  const float* bk  = (const float*)d_in[6];
  const float* Wv  = (const float*)d_in[7];
  const float* bv  = (const float*)d_in[8];
  const float* Wo  = (const float*)d_in[9];
  const float* bo  = (const float*)d_in[10];
  const float* W1  = (const float*)d_in[11];
  const float* b1  = (const float*)d_in[12];
  const float* W2  = (const float*)d_in[13];
  const float* b2  = (const float*)d_in[14];
  const float* g1  = (const float*)d_in[15];
  const float* be1 = (const float*)d_in[16];
  const float* g2  = (const float*)d_in[17];
  const float* be2 = (const float*)d_in[18];
  float* out = (float*)d_out;

  const int B = in_sizes[0] / TT_S;
  const int grid = (B + SEQ_PER_BLK - 1) / SEQ_PER_BLK;
  hipLaunchKernelGGL(tt_fused, dim3(grid), dim3(BLK), 0, stream,
                     ids, tok, pos, Wq, bq, Wk, bk, Wv, bv, Wo, bo,
                     W1, b1, W2, b2, g1, be1, g2, be2, out, B);
}

// Round 6
// 142.497 us; speedup vs baseline: 1.3892x; 1.0021x over previous
//
#include <hip/hip_runtime.h>

#define TT_S 6
#define TT_H 8
#define TT_FF 16
#define SEQ_PER_BLK 64
#define BLK 384                 /* 64 seqs * 6 tokens = 6 waves */
#define KV_STRIDE_U 52          /* uints per seq: 48 data (96 f16) + 4 pad; 52 mod 32 = 20 -> windows tile all 32 banks */

typedef __fp16 h2_t __attribute__((ext_vector_type(2)));
typedef __fp16 h8_t __attribute__((ext_vector_type(8)));

__device__ __forceinline__ unsigned pk2(float a, float b) {
  h2_t h = __builtin_amdgcn_cvt_pkrtz(a, b);
  return __builtin_bit_cast(unsigned, h);
}

__global__ __launch_bounds__(BLK, 6) void tt_fused(
    const int* __restrict__ ids,
    const float* __restrict__ tok_emb, const float* __restrict__ pos_emb,
    const float* __restrict__ Wq, const float* __restrict__ bq,
    const float* __restrict__ Wk, const float* __restrict__ bk,
    const float* __restrict__ Wv, const float* __restrict__ bv,
    const float* __restrict__ Wo, const float* __restrict__ bo,
    const float* __restrict__ W1, const float* __restrict__ b1,
    const float* __restrict__ W2, const float* __restrict__ b2,
    const float* __restrict__ g1, const float* __restrict__ be1,
    const float* __restrict__ g2, const float* __restrict__ be2,
    float* __restrict__ out, int B)
{
  // 13312 + 1600 = 14912 B LDS -> 4 blocks/CU even under a 64KB pool.
  __shared__ __align__(16) unsigned s_kv[SEQ_PER_BLK * KV_STRIDE_U];
  __shared__ __align__(16) unsigned s_tok[400];   // 800 f16 = 100 rows x 8 halves (4 uints/row)

  const int tid = threadIdx.x;
  // stage token table fp32 -> fp16 (pairs; coalesced float2 reads)
  for (int i = tid; i < 400; i += BLK) {
    float2 tv = ((const float2*)tok_emb)[i];
    s_tok[i] = pk2(tv.x, tv.y);
  }
  __syncthreads();

  const int s_loc = tid / TT_S;          // local sequence 0..63
  const int t     = tid - s_loc * TT_S;  // token row 0..5
  const int seq_g = blockIdx.x * SEQ_PER_BLK + s_loc;
  const bool valid = (seq_g < B);
  const size_t gidx = (size_t)blockIdx.x * BLK + tid;
  const int id = valid ? ids[gidx] : 0;

  // ---- x row = tok_emb[id] (f16 row = 16B = one h8_t) + pos_emb[t] (global, L1) ----
  h8_t t0 = ((const h8_t*)s_tok)[id];
  const float4* pr = (const float4*)(pos_emb + t * TT_H);
  float4 p0 = pr[0];
  float4 p1 = pr[1];
  float xs[TT_H];
  xs[0] = (float)t0[0] + p0.x; xs[1] = (float)t0[1] + p0.y;
  xs[2] = (float)t0[2] + p0.z; xs[3] = (float)t0[3] + p0.w;
  xs[4] = (float)t0[4] + p1.x; xs[5] = (float)t0[5] + p1.y;
  xs[6] = (float)t0[6] + p1.z; xs[7] = (float)t0[7] + p1.w;

  // ---- k,v for OWN token; pack f16 -> LDS ----
  {
    float kr[TT_H], vr[TT_H];
    #pragma unroll
    for (int i = 0; i < TT_H; ++i) {
      float ak = bk[i], av = bv[i];
      #pragma unroll
      for (int j = 0; j < TT_H; ++j) {
        ak = fmaf(xs[j], Wk[i*8+j], ak);
        av = fmaf(xs[j], Wv[i*8+j], av);
      }
      kr[i] = ak; vr[i] = av;
    }
    unsigned* kvp = s_kv + s_loc * KV_STRIDE_U + t * 8;
    uint4 w0, w1;
    w0.x = pk2(kr[0], kr[1]); w0.y = pk2(kr[2], kr[3]);
    w0.z = pk2(kr[4], kr[5]); w0.w = pk2(kr[6], kr[7]);
    w1.x = pk2(vr[0], vr[1]); w1.y = pk2(vr[2], vr[3]);
    w1.z = pk2(vr[4], vr[5]); w1.w = pk2(vr[6], vr[7]);
    ((uint4*)kvp)[0] = w0;
    ((uint4*)kvp)[1] = w1;
  }
  __syncthreads();

  // ---- q row (unscaled; 1/sqrt(HD)=0.5 folded into exp2 base below) ----
  float qs[TT_H];
  #pragma unroll
  for (int i = 0; i < TT_H; ++i) {
    float a = bq[i];
    #pragma unroll
    for (int j = 0; j < TT_H; ++j) a = fmaf(xs[j], Wq[i*8+j], a);
    qs[i] = a;
  }

  // ---- attention: exp(d*0.5) = 2^(d*log2(e)/2); scores small, no max-sub ----
  float acc[TT_H] = {0.f,0.f,0.f,0.f,0.f,0.f,0.f,0.f};
  float sum0 = 0.f, sum1 = 0.f;
  const h8_t* kvb = (const h8_t*)(s_kv + s_loc * KV_STRIDE_U);
  #pragma unroll
  for (int t2 = 0; t2 < TT_S; ++t2) {
    h8_t kh = kvb[t2*2];      // k dims 0..7
    h8_t vh = kvb[t2*2+1];    // v dims 0..7
    float d0 = (float)kh[0] * qs[0];
    d0 = fmaf((float)kh[1], qs[1], d0);
    d0 = fmaf((float)kh[2], qs[2], d0);
    d0 = fmaf((float)kh[3], qs[3], d0);
    float d1 = (float)kh[4] * qs[4];
    d1 = fmaf((float)kh[5], qs[5], d1);
    d1 = fmaf((float)kh[6], qs[6], d1);
    d1 = fmaf((float)kh[7], qs[7], d1);
    float e0 = __builtin_amdgcn_exp2f(d0 * 0.7213475204f);
    float e1 = __builtin_amdgcn_exp2f(d1 * 0.7213475204f);
    sum0 += e0; sum1 += e1;
    acc[0] = fmaf(e0, (float)vh[0], acc[0]);
    acc[1] = fmaf(e0, (float)vh[1], acc[1]);
    acc[2] = fmaf(e0, (float)vh[2], acc[2]);
    acc[3] = fmaf(e0, (float)vh[3], acc[3]);
    acc[4] = fmaf(e1, (float)vh[4], acc[4]);
    acc[5] = fmaf(e1, (float)vh[5], acc[5]);
    acc[6] = fmaf(e1, (float)vh[6], acc[6]);
    acc[7] = fmaf(e1, (float)vh[7], acc[7]);
  }
  {
    float inv0 = __builtin_amdgcn_rcpf(sum0);
    float inv1 = __builtin_amdgcn_rcpf(sum1);
    acc[0] *= inv0; acc[1] *= inv0; acc[2] *= inv0; acc[3] *= inv0;
    acc[4] *= inv1; acc[5] *= inv1; acc[6] *= inv1; acc[7] *= inv1;
  }

  // ---- o = attn @ Wo.T + bo; residual; LN1 ----
  float r[TT_H];
  float mu = 0.f;
  #pragma unroll
  for (int i = 0; i < TT_H; ++i) {
    float o = bo[i];
    #pragma unroll
    for (int j = 0; j < TT_H; ++j) o = fmaf(acc[j], Wo[i*8+j], o);
    r[i] = xs[i] + o;
    mu += r[i];
  }
  mu *= 0.125f;
  float var = 0.f;
  #pragma unroll
  for (int i = 0; i < TT_H; ++i) { float d = r[i] - mu; var = fmaf(d, d, var); }
  float rin = __builtin_amdgcn_rsqf(fmaf(var, 0.125f, 1e-5f));
  float mc = mu * rin;
  float hr[TT_H];
  #pragma unroll
  for (int i = 0; i < TT_H; ++i)
    hr[i] = fmaf(fmaf(r[i], rin, -mc), g1[i], be1[i]);

  // ---- ffn1: gelu(u) = u - u*rcp(e+1), e = 2^(u*(2.3022072 + 0.1029432*u^2)) ----
  float f1[TT_FF];
  #pragma unroll
  for (int f = 0; f < TT_FF; ++f) {
    float u = b1[f];
    #pragma unroll
    for (int j = 0; j < TT_H; ++j) u = fmaf(hr[j], W1[f*8+j], u);
    float u2 = u * u;
    float e  = __builtin_amdgcn_exp2f(u * fmaf(0.1029432f, u2, 2.3022072f));
    float rr = __builtin_amdgcn_rcpf(e + 1.0f);
    f1[f] = fmaf(-u, rr, u);
  }

  // ---- y = f1 @ W2.T + b2; residual; LN2; store ----
  float r2[TT_H];
  float mu2 = 0.f;
  #pragma unroll
  for (int i = 0; i < TT_H; ++i) {
    float y = b2[i];
    #pragma unroll
    for (int f = 0; f < TT_FF; ++f) y = fmaf(f1[f], W2[i*16+f], y);
    r2[i] = hr[i] + y;
    mu2 += r2[i];
  }
  mu2 *= 0.125f;
  float var2 = 0.f;
  #pragma unroll
  for (int i = 0; i < TT_H; ++i) { float d = r2[i] - mu2; var2 = fmaf(d, d, var2); }
  float rin2 = __builtin_amdgcn_rsqf(fmaf(var2, 0.125f, 1e-5f));
  float mc2 = mu2 * rin2;

  if (valid) {
    float res[TT_H];
    #pragma unroll
    for (int i = 0; i < TT_H; ++i)
      res[i] = fmaf(fmaf(r2[i], rin2, -mc2), g2[i], be2[i]);
    float* op = out + gidx * TT_H;  // consecutive lanes -> consecutive 32B: coalesced
    float4 v0; v0.x = res[0]; v0.y = res[1]; v0.z = res[2]; v0.w = res[3];
    float4 v1; v1.x = res[4]; v1.y = res[5]; v1.z = res[6]; v1.w = res[7];
    ((float4*)op)[0] = v0;
    ((float4*)op)[1] = v1;
  }
}

extern "C" void kernel_launch(void* const* d_in, const int* in_sizes, int n_in,
                              void* d_out, int out_size, void* d_ws, size_t ws_size,
                              hipStream_t stream) {
  const int*   ids = (const int*)  d_in[0];
  const float* tok = (const float*)d_in[1];
  const float* pos = (const float*)d_in[2];
  const float* Wq  = (const float*)d_in[3];
  const float* bq  = (const float*)d_in[4];
  const float* Wk  = (const float*)d_in[5];
  const float* bk  = (const float*)d_in[6];
  const float* Wv  = (const float*)d_in[7];
  const float* bv  = (const float*)d_in[8];
  const float* Wo  = (const float*)d_in[9];
  const float* bo  = (const float*)d_in[10];
  const float* W1  = (const float*)d_in[11];
  const float* b1  = (const float*)d_in[12];
  const float* W2  = (const float*)d_in[13];
  const float* b2  = (const float*)d_in[14];
  const float* g1  = (const float*)d_in[15];
  const float* be1 = (const float*)d_in[16];
  const float* g2  = (const float*)d_in[17];
  const float* be2 = (const float*)d_in[18];
  float* out = (float*)d_out;

  const int B = in_sizes[0] / TT_S;
  const int grid = (B + SEQ_PER_BLK - 1) / SEQ_PER_BLK;
  hipLaunchKernelGGL(tt_fused, dim3(grid), dim3(BLK), 0, stream,
                     ids, tok, pos, Wq, bq, Wk, bk, Wv, bv, Wo, bo,
                     W1, b1, W2, b2, g1, be1, g2, be2, out, B);
}